// Round 8
// baseline (15391.611 us; speedup 1.0000x reference)
//
#include <hip/hip_runtime.h>
#include <cstddef>

#define NB   256   // batch
#define TT   300   // timesteps
#define SS   150   // input feature dim
#define HH   100   // hidden
#define G4   400   // 4*H gates
#define NCLS 60

__device__ __forceinline__ float sigf(float x) {
    float e = __expf(-x);
    return 1.f / (1.f + e);
}
__device__ __forceinline__ float tanh_fast(float x) {
    float e = __expf(2.f * x);
    return 1.f - 2.f / (e + 1.f);
}

// ---- AGPR parking for the recurrent weights --------------------------------
// R1-R7 post-mortems: the allocator remats plain loads (R1/R2/R4/R6) or
// spills asm-opaque loads (R5/R7) -- it never keeps ~50 loop-invariant floats
// in VGPRs. Fix: hold the 100 weights in HARD-CODED physical AGPRs a0-a99
// (gfx950 unified RF). Volatile asm on fixed physical regs cannot be
// rematerialized, sunk, or spilled; full clobber lists keep the allocator
// from placing its own values there.
#define AGCLOB \
  "a0","a1","a2","a3","a4","a5","a6","a7","a8","a9", \
  "a10","a11","a12","a13","a14","a15","a16","a17","a18","a19", \
  "a20","a21","a22","a23","a24","a25","a26","a27","a28","a29", \
  "a30","a31","a32","a33","a34","a35","a36","a37","a38","a39", \
  "a40","a41","a42","a43","a44","a45","a46","a47","a48","a49", \
  "a50","a51","a52","a53","a54","a55","a56","a57","a58","a59", \
  "a60","a61","a62","a63","a64","a65","a66","a67","a68","a69", \
  "a70","a71","a72","a73","a74","a75","a76","a77","a78","a79", \
  "a80","a81","a82","a83","a84","a85","a86","a87","a88","a89", \
  "a90","a91","a92","a93","a94","a95","a96","a97","a98","a99"

#define AGW4(R0,R1,R2,R3, V) \
  asm volatile("v_accvgpr_write_b32 " R0 ", %0\n\t" \
               "v_accvgpr_write_b32 " R1 ", %1\n\t" \
               "v_accvgpr_write_b32 " R2 ", %2\n\t" \
               "v_accvgpr_write_b32 " R3 ", %3" \
               :: "v"((V).x), "v"((V).y), "v"((V).z), "v"((V).w) : AGCLOB)

#define LOADW4(J, R0,R1,R2,R3) { float4 v_ = wrow[J]; AGW4(R0,R1,R2,R3, v_); }

#define DOT4(J, R0,R1,R2,R3, ACC) { \
    float4 hv_ = h4[J]; float w0_, w1_, w2_, w3_; \
    asm volatile("v_accvgpr_read_b32 %0, " R0 "\n\t" \
                 "v_accvgpr_read_b32 %1, " R1 "\n\t" \
                 "v_accvgpr_read_b32 %2, " R2 "\n\t" \
                 "v_accvgpr_read_b32 %3, " R3 \
                 : "=v"(w0_), "=v"(w1_), "=v"(w2_), "=v"(w3_) :: AGCLOB); \
    ACC = fmaf(hv_.x, w0_, fmaf(hv_.y, w1_, fmaf(hv_.z, w2_, fmaf(hv_.w, w3_, ACC)))); }

// ---------------------------------------------------------------------------
// GEMM: C[M x 400] = A[M x K] * W[400 x K]^T + (bih + bhh)   (unchanged)
// ---------------------------------------------------------------------------
template<int K>
__global__ __launch_bounds__(256, 2) void gemm_inproj(
    const float* __restrict__ A, const float* __restrict__ W,
    const float* __restrict__ bih, const float* __restrict__ bhh,
    float* __restrict__ C)
{
    __shared__ float As[K][64];
    __shared__ float Bs[K][64];
    const int m0 = blockIdx.x * 64;
    const int n0 = blockIdx.y * 64;
    const int tid = threadIdx.x;
    const int r = tid & 63;
    constexpr int K2 = K / 2;

    for (int i = tid; i < 64 * K2; i += 256) {
        int c2 = i >> 6;
        float2 v = *(const float2*)(A + (size_t)(m0 + r) * K + 2 * c2);
        As[2 * c2][r] = v.x;
        As[2 * c2 + 1][r] = v.y;
    }
    {
        int g = n0 + r;
        if (g < G4) {
            for (int i = tid; i < 64 * K2; i += 256) {
                int c2 = i >> 6;
                float2 v = *(const float2*)(W + (size_t)g * K + 2 * c2);
                Bs[2 * c2][r] = v.x;
                Bs[2 * c2 + 1][r] = v.y;
            }
        } else {
            for (int i = tid; i < 64 * K2; i += 256) {
                int c2 = i >> 6;
                Bs[2 * c2][r] = 0.f;
                Bs[2 * c2 + 1][r] = 0.f;
            }
        }
    }
    __syncthreads();

    const int tx = tid & 15, ty = tid >> 4;
    float acc[4][4] = {};
#pragma unroll 10
    for (int k = 0; k < K; ++k) {
        float4 a = *(const float4*)&As[k][ty * 4];
        float4 b = *(const float4*)&Bs[k][tx * 4];
        acc[0][0] += a.x * b.x; acc[0][1] += a.x * b.y; acc[0][2] += a.x * b.z; acc[0][3] += a.x * b.w;
        acc[1][0] += a.y * b.x; acc[1][1] += a.y * b.y; acc[1][2] += a.y * b.z; acc[1][3] += a.y * b.w;
        acc[2][0] += a.z * b.x; acc[2][1] += a.z * b.y; acc[2][2] += a.z * b.z; acc[2][3] += a.z * b.w;
        acc[3][0] += a.w * b.x; acc[3][1] += a.w * b.y; acc[3][2] += a.w * b.z; acc[3][3] += a.w * b.w;
    }

    const int g0 = n0 + tx * 4;
    if (g0 + 3 < G4) {
        float b0 = bih[g0] + bhh[g0];
        float b1 = bih[g0 + 1] + bhh[g0 + 1];
        float b2 = bih[g0 + 2] + bhh[g0 + 2];
        float b3 = bih[g0 + 3] + bhh[g0 + 3];
#pragma unroll
        for (int i = 0; i < 4; ++i) {
            float4 o;
            o.x = acc[i][0] + b0; o.y = acc[i][1] + b1;
            o.z = acc[i][2] + b2; o.w = acc[i][3] + b3;
            *(float4*)(C + (size_t)(m0 + ty * 4 + i) * G4 + g0) = o;
        }
    }
}

// ---------------------------------------------------------------------------
// LSTM recurrence, AGPR-resident weights. One block (448 thr, 7 waves) / seq.
// Thread g<400 owns gate row g: its 100 Whh weights live in a0-a99 (written
// once via v_accvgpr_write, read each step via v_accvgpr_read -- the
// allocator can't remat or spill physical AGPRs). h broadcast: same-address
// ds_read_b128 (LDS broadcast). Gates combine in gate_lds[400].
// MODE 0: rot+tr fused (512 blocks). MODE 1: write h seq. MODE 2: mean+fc+sm.
// ---------------------------------------------------------------------------
template<int MODE>
__global__ __launch_bounds__(448) void lstm_rec(
    const float* __restrict__ xgA, const float* __restrict__ xgB,
    const float* __restrict__ WhhA, const float* __restrict__ WhhB,
    const float* __restrict__ fwA, const float* __restrict__ fbA,
    const float* __restrict__ fwB, const float* __restrict__ fbB,
    float* __restrict__ oA, float* __restrict__ oB)
{
    constexpr int FSZ = (MODE == 2) ? (NCLS * HH + NCLS) : (3 * HH + 4);
    __shared__ float h_lds[104];
    __shared__ float gate_lds[G4];
    __shared__ float fcw[FSZ];

    const int tid = threadIdx.x;
    int n = blockIdx.x;
    const float* xg = xgA;
    const float* whh = WhhA;
    const float* fw = fwA;
    const float* fb = fbA;
    float* op = oA;
    if (MODE == 0 && blockIdx.x >= NB) {
        n = blockIdx.x - NB;
        xg = xgB; whh = WhhB; fw = fwB; fb = fbB; op = oB;
    }

    const int g = tid;
    const bool act = (g < G4);
    const int gsafe = act ? g : 0;          // clamp inactive threads
    const float4* wrow = (const float4*)(whh + (size_t)gsafe * HH);

    // ---- park Whh[g][0..99] in a0..a99 (uniform control flow, all lanes)
    LOADW4(0,  "a0","a1","a2","a3");   LOADW4(1,  "a4","a5","a6","a7");
    LOADW4(2,  "a8","a9","a10","a11"); LOADW4(3,  "a12","a13","a14","a15");
    LOADW4(4,  "a16","a17","a18","a19");LOADW4(5,  "a20","a21","a22","a23");
    LOADW4(6,  "a24","a25","a26","a27");LOADW4(7,  "a28","a29","a30","a31");
    LOADW4(8,  "a32","a33","a34","a35");LOADW4(9,  "a36","a37","a38","a39");
    LOADW4(10, "a40","a41","a42","a43");LOADW4(11, "a44","a45","a46","a47");
    LOADW4(12, "a48","a49","a50","a51");LOADW4(13, "a52","a53","a54","a55");
    LOADW4(14, "a56","a57","a58","a59");LOADW4(15, "a60","a61","a62","a63");
    LOADW4(16, "a64","a65","a66","a67");LOADW4(17, "a68","a69","a70","a71");
    LOADW4(18, "a72","a73","a74","a75");LOADW4(19, "a76","a77","a78","a79");
    LOADW4(20, "a80","a81","a82","a83");LOADW4(21, "a84","a85","a86","a87");
    LOADW4(22, "a88","a89","a90","a91");LOADW4(23, "a92","a93","a94","a95");
    LOADW4(24, "a96","a97","a98","a99");

    if (tid < 104) h_lds[tid] = 0.f;
    if (MODE == 0) {
        for (int i = tid; i < 3 * HH; i += 448) fcw[i] = fw[i];
        if (tid < 3) fcw[3 * HH + tid] = fb[tid];
    }
    if (MODE == 2) {
        for (int i = tid; i < NCLS * HH; i += 448) fcw[i] = fw[i];
        if (tid < NCLS) fcw[NCLS * HH + tid] = fb[tid];
    }
    float c = 0.f, hsum = 0.f;
    __syncthreads();

    const float4* h4 = (const float4*)h_lds;
    const float* xgn = xg + (size_t)n * TT * G4 + g;
    float x0 = 0.f, x1 = 0.f;
    if (act) { x0 = xgn[0]; x1 = xgn[G4]; }

    for (int t = 0; t < TT; ++t) {
        float s0 = act ? x0 : 0.f;
        float s1 = 0.f, s2 = 0.f, s3 = 0.f;
        x0 = x1;
        if (act && t + 2 < TT) x1 = xgn[(size_t)(t + 2) * G4];

        DOT4(0,  "a0","a1","a2","a3",     s0);
        DOT4(1,  "a4","a5","a6","a7",     s1);
        DOT4(2,  "a8","a9","a10","a11",   s2);
        DOT4(3,  "a12","a13","a14","a15", s3);
        DOT4(4,  "a16","a17","a18","a19", s0);
        DOT4(5,  "a20","a21","a22","a23", s1);
        DOT4(6,  "a24","a25","a26","a27", s2);
        DOT4(7,  "a28","a29","a30","a31", s3);
        DOT4(8,  "a32","a33","a34","a35", s0);
        DOT4(9,  "a36","a37","a38","a39", s1);
        DOT4(10, "a40","a41","a42","a43", s2);
        DOT4(11, "a44","a45","a46","a47", s3);
        DOT4(12, "a48","a49","a50","a51", s0);
        DOT4(13, "a52","a53","a54","a55", s1);
        DOT4(14, "a56","a57","a58","a59", s2);
        DOT4(15, "a60","a61","a62","a63", s3);
        DOT4(16, "a64","a65","a66","a67", s0);
        DOT4(17, "a68","a69","a70","a71", s1);
        DOT4(18, "a72","a73","a74","a75", s2);
        DOT4(19, "a76","a77","a78","a79", s3);
        DOT4(20, "a80","a81","a82","a83", s0);
        DOT4(21, "a84","a85","a86","a87", s1);
        DOT4(22, "a88","a89","a90","a91", s2);
        DOT4(23, "a92","a93","a94","a95", s3);
        DOT4(24, "a96","a97","a98","a99", s0);

        if (act) gate_lds[g] = (s0 + s1) + (s2 + s3);
        __syncthreads();

        if (tid < HH) {
            float ig = sigf(gate_lds[tid]);
            float fg = sigf(gate_lds[tid + HH]);
            float gg = tanh_fast(gate_lds[tid + 2 * HH]);
            float og = sigf(gate_lds[tid + 3 * HH]);
            c = fg * c + ig * gg;
            float h = og * tanh_fast(c);
            h_lds[tid] = h;
            if (MODE == 1) op[((size_t)n * TT + t) * HH + tid] = h;
            if (MODE == 2) hsum += h;
        }
        __syncthreads();

        if (MODE == 0 && tid < 64) {
            // wave0's fc of h_t; safe: next h write is behind the next
            // barrier, which wave0 only reaches after finishing this.
            float p0 = 0.f, p1 = 0.f, p2 = 0.f;
            for (int k = tid; k < HH; k += 64) {
                float hk = h_lds[k];
                p0 += hk * fcw[k];
                p1 += hk * fcw[HH + k];
                p2 += hk * fcw[2 * HH + k];
            }
#pragma unroll
            for (int s = 32; s; s >>= 1) {
                p0 += __shfl_xor(p0, s);
                p1 += __shfl_xor(p1, s);
                p2 += __shfl_xor(p2, s);
            }
            if (tid == 0) {
                size_t o = ((size_t)n * TT + t) * 3;
                op[o] = p0 + fcw[3 * HH];
                op[o + 1] = p1 + fcw[3 * HH + 1];
                op[o + 2] = p2 + fcw[3 * HH + 2];
            }
        }
    }

    if (MODE == 2) {
        if (tid < HH) h_lds[tid] = hsum * (1.f / TT);
        __syncthreads();
        if (tid < 64) {
            float logit = -3.0e38f;
            if (tid < NCLS) {
                float a = fcw[NCLS * HH + tid];
#pragma unroll
                for (int k = 0; k < HH; ++k) a += h_lds[k] * fcw[tid * HH + k];
                logit = a;
            }
            float mx = logit;
#pragma unroll
            for (int s = 32; s; s >>= 1) mx = fmaxf(mx, __shfl_xor(mx, s));
            float e = (tid < NCLS) ? __expf(logit - mx) : 0.f;
            float sum = e;
#pragma unroll
            for (int s = 32; s; s >>= 1) sum += __shfl_xor(sum, s);
            if (tid < NCLS) op[(size_t)n * NCLS + tid] = e / sum;
        }
    }
}

// ---------------------------------------------------------------------------
// Rotation/translation transform (unchanged)
// ---------------------------------------------------------------------------
__global__ __launch_bounds__(256) void transform_pts(
    const float* __restrict__ x, const float* __restrict__ rot,
    const float* __restrict__ tr, float* __restrict__ xr)
{
    const int idx = blockIdx.x * 4 + (threadIdx.x >> 6);
    const int lane = threadIdx.x & 63;
    const float* ang = rot + (size_t)idx * 3;
    float a = ang[0], b = ang[1], cg = ang[2];
    float ca = cosf(a), sa = sinf(a);
    float cb = cosf(b), sb = sinf(b);
    float cc = cosf(cg), sc = sinf(cg);
    float R00 = cc * cb, R01 = cc * sb * sa + sc * ca, R02 = -cc * sb * ca + sc * sa;
    float R10 = -sc * cb, R11 = -sc * sb * sa + cc * ca, R12 = sc * sb * ca + cc * sa;
    float R20 = sb, R21 = -cb * sa, R22 = cb * ca;
    float t0 = tr[(size_t)idx * 3], t1 = tr[(size_t)idx * 3 + 1], t2 = tr[(size_t)idx * 3 + 2];
    if (lane < 50) {
        const float* xp = x + (size_t)idx * SS + lane * 3;
        float p0 = xp[0] - t0, p1 = xp[1] - t1, p2 = xp[2] - t2;
        float* o = xr + (size_t)idx * SS + lane * 3;
        o[0] = R00 * p0 + R01 * p1 + R02 * p2;
        o[1] = R10 * p0 + R11 * p1 + R12 * p2;
        o[2] = R20 * p0 + R21 * p1 + R22 * p2;
    }
}

// ---------------------------------------------------------------------------
extern "C" void kernel_launch(void* const* d_in, const int* in_sizes, int n_in,
                              void* d_out, int out_size, void* d_ws, size_t ws_size,
                              hipStream_t stream)
{
    const float* x       = (const float*)d_in[0];
    const float* rot_Wih = (const float*)d_in[1];
    const float* rot_Whh = (const float*)d_in[2];
    const float* rot_bih = (const float*)d_in[3];
    const float* rot_bhh = (const float*)d_in[4];
    const float* tr_Wih  = (const float*)d_in[5];
    const float* tr_Whh  = (const float*)d_in[6];
    const float* tr_bih  = (const float*)d_in[7];
    const float* tr_bhh  = (const float*)d_in[8];
    const float* rot_fcW = (const float*)d_in[9];
    const float* rot_fcb = (const float*)d_in[10];
    const float* tr_fcW  = (const float*)d_in[11];
    const float* tr_fcb  = (const float*)d_in[12];
    const float* W0 = (const float*)d_in[13];
    const float* U0 = (const float*)d_in[14];
    const float* b0i = (const float*)d_in[15];
    const float* b0h = (const float*)d_in[16];
    const float* W1 = (const float*)d_in[17];
    const float* U1 = (const float*)d_in[18];
    const float* b1i = (const float*)d_in[19];
    const float* b1h = (const float*)d_in[20];
    const float* W2 = (const float*)d_in[21];
    const float* U2 = (const float*)d_in[22];
    const float* b2i = (const float*)d_in[23];
    const float* b2h = (const float*)d_in[24];
    const float* fcW = (const float*)d_in[25];
    const float* fcb = (const float*)d_in[26];
    float* out = (float*)d_out;

    float* ws = (float*)d_ws;
    float* xgA  = ws;
    float* xgB  = ws + 30720000ull;
    float* rotA = ws + 61440000ull;
    float* trO  = ws + 61670400ull;
    float* xr = xgA;
    float* h0 = xgA + 11520000ull;
    float* h1 = xgA + 19200000ull;

    dim3 gg(1200, 7), bb(256);
    gemm_inproj<150><<<gg, bb, 0, stream>>>(x, rot_Wih, rot_bih, rot_bhh, xgA);
    gemm_inproj<150><<<gg, bb, 0, stream>>>(x, tr_Wih, tr_bih, tr_bhh, xgB);
    lstm_rec<0><<<512, 448, 0, stream>>>(xgA, xgB, rot_Whh, tr_Whh,
                                         rot_fcW, rot_fcb, tr_fcW, tr_fcb,
                                         rotA, trO);
    transform_pts<<<19200, 256, 0, stream>>>(x, rotA, trO, xr);
    gemm_inproj<150><<<gg, bb, 0, stream>>>(xr, W0, b0i, b0h, xgB);
    lstm_rec<1><<<256, 448, 0, stream>>>(xgB, nullptr, U0, nullptr,
                                         nullptr, nullptr, nullptr, nullptr,
                                         h0, nullptr);
    gemm_inproj<100><<<gg, bb, 0, stream>>>(h0, W1, b1i, b1h, xgB);
    lstm_rec<1><<<256, 448, 0, stream>>>(xgB, nullptr, U1, nullptr,
                                         nullptr, nullptr, nullptr, nullptr,
                                         h1, nullptr);
    gemm_inproj<100><<<gg, bb, 0, stream>>>(h1, W2, b2i, b2h, xgB);
    lstm_rec<2><<<256, 448, 0, stream>>>(xgB, nullptr, U2, nullptr,
                                         fcW, fcb, nullptr, nullptr,
                                         out, nullptr);
}

// Round 9
// 3397.342 us; speedup vs baseline: 4.5305x; 4.5305x over previous
//
#include <hip/hip_runtime.h>
#include <cstddef>

#define NB   256   // batch
#define TT   300   // timesteps
#define SS   150   // input feature dim
#define HH   100   // hidden
#define G4   400   // 4*H gates
#define NCLS 60

__device__ __forceinline__ float sigf(float x) {
    float e = __expf(-x);
    return 1.f / (1.f + e);
}
__device__ __forceinline__ float tanh_fast(float x) {
    float e = __expf(2.f * x);
    return 1.f - 2.f / (e + 1.f);
}
__device__ __forceinline__ float rlane(float v, int l) {
    return __int_as_float(__builtin_amdgcn_readlane(__float_as_int(v), l));
}

// ---------------------------------------------------------------------------
// GEMM: C[M x 400] = A[M x K] * W[400 x K]^T + (bih + bhh)   (unchanged)
// ---------------------------------------------------------------------------
template<int K>
__global__ __launch_bounds__(256, 2) void gemm_inproj(
    const float* __restrict__ A, const float* __restrict__ W,
    const float* __restrict__ bih, const float* __restrict__ bhh,
    float* __restrict__ C)
{
    __shared__ float As[K][64];
    __shared__ float Bs[K][64];
    const int m0 = blockIdx.x * 64;
    const int n0 = blockIdx.y * 64;
    const int tid = threadIdx.x;
    const int r = tid & 63;
    constexpr int K2 = K / 2;

    for (int i = tid; i < 64 * K2; i += 256) {
        int c2 = i >> 6;
        float2 v = *(const float2*)(A + (size_t)(m0 + r) * K + 2 * c2);
        As[2 * c2][r] = v.x;
        As[2 * c2 + 1][r] = v.y;
    }
    {
        int g = n0 + r;
        if (g < G4) {
            for (int i = tid; i < 64 * K2; i += 256) {
                int c2 = i >> 6;
                float2 v = *(const float2*)(W + (size_t)g * K + 2 * c2);
                Bs[2 * c2][r] = v.x;
                Bs[2 * c2 + 1][r] = v.y;
            }
        } else {
            for (int i = tid; i < 64 * K2; i += 256) {
                int c2 = i >> 6;
                Bs[2 * c2][r] = 0.f;
                Bs[2 * c2 + 1][r] = 0.f;
            }
        }
    }
    __syncthreads();

    const int tx = tid & 15, ty = tid >> 4;
    float acc[4][4] = {};
#pragma unroll 10
    for (int k = 0; k < K; ++k) {
        float4 a = *(const float4*)&As[k][ty * 4];
        float4 b = *(const float4*)&Bs[k][tx * 4];
        acc[0][0] += a.x * b.x; acc[0][1] += a.x * b.y; acc[0][2] += a.x * b.z; acc[0][3] += a.x * b.w;
        acc[1][0] += a.y * b.x; acc[1][1] += a.y * b.y; acc[1][2] += a.y * b.z; acc[1][3] += a.y * b.w;
        acc[2][0] += a.z * b.x; acc[2][1] += a.z * b.y; acc[2][2] += a.z * b.z; acc[2][3] += a.z * b.w;
        acc[3][0] += a.w * b.x; acc[3][1] += a.w * b.y; acc[3][2] += a.w * b.z; acc[3][3] += a.w * b.w;
    }

    const int g0 = n0 + tx * 4;
    if (g0 + 3 < G4) {
        float b0 = bih[g0] + bhh[g0];
        float b1 = bih[g0 + 1] + bhh[g0 + 1];
        float b2 = bih[g0 + 2] + bhh[g0 + 2];
        float b3 = bih[g0 + 3] + bhh[g0 + 3];
#pragma unroll
        for (int i = 0; i < 4; ++i) {
            float4 o;
            o.x = acc[i][0] + b0; o.y = acc[i][1] + b1;
            o.z = acc[i][2] + b2; o.w = acc[i][3] + b3;
            *(float4*)(C + (size_t)(m0 + ty * 4 + i) * G4 + g0) = o;
        }
    }
}

// ---------------------------------------------------------------------------
// LSTM recurrence, LDS-resident weights. One block (512 thr, 8 waves) / seq.
// R1-R8 lesson: the allocator will NOT keep ~100 loop-invariant floats in
// registers (remats plain loads, spills opaque ones, melts down on physical
// AGPR pins). So design for ~40 VGPRs: Whh lives in LDS (160,000 B fp32;
// gfx950 allows up to 163,840 B/workgroup). Thread g owns gate row g and
// reads it with 25 ds_read_b128/step (row pitch 400 B = 16B-aligned; lane
// stride 100 dwords -> bank stride 4 -> 16-lane quarter tiles 32 banks
// exactly 2x = inherent minimum, conflict-free). h broadcast: 2 ds_read_b32
// per thread + compile-time readlane. Gates combine in gate_lds[400].
// MODE 0: rot+tr fused (512 blocks). MODE 1: write h seq.
// MODE 2: mean+fc+softmax with fc weights read from GLOBAL (LDS is full).
// ---------------------------------------------------------------------------
template<int MODE>
__global__ __launch_bounds__(512) void lstm_rec(
    const float* __restrict__ xgA, const float* __restrict__ xgB,
    const float* __restrict__ WhhA, const float* __restrict__ WhhB,
    const float* __restrict__ fwA, const float* __restrict__ fbA,
    const float* __restrict__ fwB, const float* __restrict__ fbB,
    float* __restrict__ oA, float* __restrict__ oB)
{
    constexpr int FSZ = (MODE == 0) ? (3 * HH + 4) : 4;
    __shared__ float wlds[G4 * HH];   // 160,000 B
    __shared__ float h_lds[128];      // h + zero pad for hhi reads
    __shared__ float gate_lds[G4];
    __shared__ float fcw[FSZ];

    const int tid = threadIdx.x;
    int n = blockIdx.x;
    const float* xg = xgA;
    const float* whh = WhhA;
    const float* fw = fwA;
    const float* fb = fbA;
    float* op = oA;
    if (MODE == 0 && blockIdx.x >= NB) {
        n = blockIdx.x - NB;
        xg = xgB; whh = WhhB; fw = fwB; fb = fbB; op = oB;
    }

    // ---- stage Whh into LDS (row-major, contiguous float4 copy)
    {
        const float4* src = (const float4*)whh;
        float4* dst = (float4*)wlds;
        for (int i = tid; i < G4 * HH / 4; i += 512) dst[i] = src[i];
    }
    if (tid < 128) h_lds[tid] = 0.f;
    if (MODE == 0) {
        for (int i = tid; i < 3 * HH; i += 512) fcw[i] = fw[i];
        if (tid < 3) fcw[3 * HH + tid] = fb[tid];
    }
    float c = 0.f, hsum = 0.f;
    __syncthreads();

    const int lane = tid & 63;
    const int g = tid;
    const bool act = (g < G4);
    const int gsafe = act ? g : 0;
    const float4* wrow = (const float4*)(wlds + gsafe * HH);

    const float* xgn = xg + (size_t)n * TT * G4 + g;
    float x0 = 0.f, x1 = 0.f;
    if (act) { x0 = xgn[0]; x1 = xgn[G4]; }

    for (int t = 0; t < TT; ++t) {
        // wave's h copy: lane l holds h[l] and h[64+l] (pad region is 0)
        float hlo = h_lds[lane];
        float hhi = h_lds[64 + lane];

        float s0 = act ? x0 : 0.f;
        float s1 = 0.f, s2 = 0.f, s3 = 0.f;
        x0 = x1;
        if (act && t + 2 < TT) x1 = xgn[(size_t)(t + 2) * G4];

#pragma unroll
        for (int j = 0; j < 25; ++j) {
            float4 wv = wrow[j];
            const int k = 4 * j;
            float h0 = (k + 0 < 64) ? rlane(hlo, (k + 0) & 63) : rlane(hhi, (k + 0) & 63);
            float h1 = (k + 1 < 64) ? rlane(hlo, (k + 1) & 63) : rlane(hhi, (k + 1) & 63);
            float h2 = (k + 2 < 64) ? rlane(hlo, (k + 2) & 63) : rlane(hhi, (k + 2) & 63);
            float h3 = (k + 3 < 64) ? rlane(hlo, (k + 3) & 63) : rlane(hhi, (k + 3) & 63);
            switch (j & 3) {
            case 0: s0 = fmaf(h0, wv.x, fmaf(h1, wv.y, fmaf(h2, wv.z, fmaf(h3, wv.w, s0)))); break;
            case 1: s1 = fmaf(h0, wv.x, fmaf(h1, wv.y, fmaf(h2, wv.z, fmaf(h3, wv.w, s1)))); break;
            case 2: s2 = fmaf(h0, wv.x, fmaf(h1, wv.y, fmaf(h2, wv.z, fmaf(h3, wv.w, s2)))); break;
            default: s3 = fmaf(h0, wv.x, fmaf(h1, wv.y, fmaf(h2, wv.z, fmaf(h3, wv.w, s3)))); break;
            }
        }

        if (act) gate_lds[g] = (s0 + s1) + (s2 + s3);
        __syncthreads();

        if (tid < HH) {
            float ig = sigf(gate_lds[tid]);
            float fg = sigf(gate_lds[tid + HH]);
            float gg = tanh_fast(gate_lds[tid + 2 * HH]);
            float og = sigf(gate_lds[tid + 3 * HH]);
            c = fg * c + ig * gg;
            float h = og * tanh_fast(c);
            h_lds[tid] = h;
            if (MODE == 1) op[((size_t)n * TT + t) * HH + tid] = h;
            if (MODE == 2) hsum += h;
        }
        __syncthreads();

        if (MODE == 0 && tid < 64) {
            // wave0's fc of h_t; safe: next h write is behind the next
            // barrier, which wave0 only reaches after finishing this.
            float p0 = 0.f, p1 = 0.f, p2 = 0.f;
            for (int k = tid; k < HH; k += 64) {
                float hk = h_lds[k];
                p0 += hk * fcw[k];
                p1 += hk * fcw[HH + k];
                p2 += hk * fcw[2 * HH + k];
            }
#pragma unroll
            for (int s = 32; s; s >>= 1) {
                p0 += __shfl_xor(p0, s);
                p1 += __shfl_xor(p1, s);
                p2 += __shfl_xor(p2, s);
            }
            if (tid == 0) {
                size_t o = ((size_t)n * TT + t) * 3;
                op[o] = p0 + fcw[3 * HH];
                op[o + 1] = p1 + fcw[3 * HH + 1];
                op[o + 2] = p2 + fcw[3 * HH + 2];
            }
        }
    }

    if (MODE == 2) {
        if (tid < HH) h_lds[tid] = hsum * (1.f / TT);
        __syncthreads();
        if (tid < 64) {
            float logit = -3.0e38f;
            if (tid < NCLS) {
                float a = fb[tid];          // fc weights from global (L2-hot)
                const float* fr = fw + tid * HH;
#pragma unroll 10
                for (int k = 0; k < HH; ++k) a += h_lds[k] * fr[k];
                logit = a;
            }
            float mx = logit;
#pragma unroll
            for (int s = 32; s; s >>= 1) mx = fmaxf(mx, __shfl_xor(mx, s));
            float e = (tid < NCLS) ? __expf(logit - mx) : 0.f;
            float sum = e;
#pragma unroll
            for (int s = 32; s; s >>= 1) sum += __shfl_xor(sum, s);
            if (tid < NCLS) op[(size_t)n * NCLS + tid] = e / sum;
        }
    }
}

// ---------------------------------------------------------------------------
// Rotation/translation transform (unchanged)
// ---------------------------------------------------------------------------
__global__ __launch_bounds__(256) void transform_pts(
    const float* __restrict__ x, const float* __restrict__ rot,
    const float* __restrict__ tr, float* __restrict__ xr)
{
    const int idx = blockIdx.x * 4 + (threadIdx.x >> 6);
    const int lane = threadIdx.x & 63;
    const float* ang = rot + (size_t)idx * 3;
    float a = ang[0], b = ang[1], cg = ang[2];
    float ca = cosf(a), sa = sinf(a);
    float cb = cosf(b), sb = sinf(b);
    float cc = cosf(cg), sc = sinf(cg);
    float R00 = cc * cb, R01 = cc * sb * sa + sc * ca, R02 = -cc * sb * ca + sc * sa;
    float R10 = -sc * cb, R11 = -sc * sb * sa + cc * ca, R12 = sc * sb * ca + cc * sa;
    float R20 = sb, R21 = -cb * sa, R22 = cb * ca;
    float t0 = tr[(size_t)idx * 3], t1 = tr[(size_t)idx * 3 + 1], t2 = tr[(size_t)idx * 3 + 2];
    if (lane < 50) {
        const float* xp = x + (size_t)idx * SS + lane * 3;
        float p0 = xp[0] - t0, p1 = xp[1] - t1, p2 = xp[2] - t2;
        float* o = xr + (size_t)idx * SS + lane * 3;
        o[0] = R00 * p0 + R01 * p1 + R02 * p2;
        o[1] = R10 * p0 + R11 * p1 + R12 * p2;
        o[2] = R20 * p0 + R21 * p1 + R22 * p2;
    }
}

// ---------------------------------------------------------------------------
extern "C" void kernel_launch(void* const* d_in, const int* in_sizes, int n_in,
                              void* d_out, int out_size, void* d_ws, size_t ws_size,
                              hipStream_t stream)
{
    const float* x       = (const float*)d_in[0];
    const float* rot_Wih = (const float*)d_in[1];
    const float* rot_Whh = (const float*)d_in[2];
    const float* rot_bih = (const float*)d_in[3];
    const float* rot_bhh = (const float*)d_in[4];
    const float* tr_Wih  = (const float*)d_in[5];
    const float* tr_Whh  = (const float*)d_in[6];
    const float* tr_bih  = (const float*)d_in[7];
    const float* tr_bhh  = (const float*)d_in[8];
    const float* rot_fcW = (const float*)d_in[9];
    const float* rot_fcb = (const float*)d_in[10];
    const float* tr_fcW  = (const float*)d_in[11];
    const float* tr_fcb  = (const float*)d_in[12];
    const float* W0 = (const float*)d_in[13];
    const float* U0 = (const float*)d_in[14];
    const float* b0i = (const float*)d_in[15];
    const float* b0h = (const float*)d_in[16];
    const float* W1 = (const float*)d_in[17];
    const float* U1 = (const float*)d_in[18];
    const float* b1i = (const float*)d_in[19];
    const float* b1h = (const float*)d_in[20];
    const float* W2 = (const float*)d_in[21];
    const float* U2 = (const float*)d_in[22];
    const float* b2i = (const float*)d_in[23];
    const float* b2h = (const float*)d_in[24];
    const float* fcW = (const float*)d_in[25];
    const float* fcb = (const float*)d_in[26];
    float* out = (float*)d_out;

    float* ws = (float*)d_ws;
    float* xgA  = ws;
    float* xgB  = ws + 30720000ull;
    float* rotA = ws + 61440000ull;
    float* trO  = ws + 61670400ull;
    float* xr = xgA;
    float* h0 = xgA + 11520000ull;
    float* h1 = xgA + 19200000ull;

    dim3 gg(1200, 7), bb(256);
    gemm_inproj<150><<<gg, bb, 0, stream>>>(x, rot_Wih, rot_bih, rot_bhh, xgA);
    gemm_inproj<150><<<gg, bb, 0, stream>>>(x, tr_Wih, tr_bih, tr_bhh, xgB);
    lstm_rec<0><<<512, 512, 0, stream>>>(xgA, xgB, rot_Whh, tr_Whh,
                                         rot_fcW, rot_fcb, tr_fcW, tr_fcb,
                                         rotA, trO);
    transform_pts<<<19200, 256, 0, stream>>>(x, rotA, trO, xr);
    gemm_inproj<150><<<gg, bb, 0, stream>>>(xr, W0, b0i, b0h, xgB);
    lstm_rec<1><<<256, 512, 0, stream>>>(xgB, nullptr, U0, nullptr,
                                         nullptr, nullptr, nullptr, nullptr,
                                         h0, nullptr);
    gemm_inproj<100><<<gg, bb, 0, stream>>>(h0, W1, b1i, b1h, xgB);
    lstm_rec<1><<<256, 512, 0, stream>>>(xgB, nullptr, U1, nullptr,
                                         nullptr, nullptr, nullptr, nullptr,
                                         h1, nullptr);
    gemm_inproj<100><<<gg, bb, 0, stream>>>(h1, W2, b2i, b2h, xgB);
    lstm_rec<2><<<256, 512, 0, stream>>>(xgB, nullptr, U2, nullptr,
                                         fcW, fcb, nullptr, nullptr,
                                         out, nullptr);
}